// Round 8
// baseline (261.100 us; speedup 1.0000x reference)
//
#include <hip/hip_runtime.h>
#include <hip/hip_bf16.h>

// B=2, S=768, H=768, NH=12, D=64, NKEY=9216. Output fp32 [B][S][NH][D].
// Round 8: (1) fused prep kernel casts W^T/hid/memk/memv to bf16 once ->
// all GEMMs run pure-bf16 operands (half traffic, no per-slab cvt);
// (2) combine re-gridded to 576 blocks; (3) flash goes triple-buffered DMA
// with raw s_waitcnt vmcnt(8)+s_barrier per tile (prefetch distance 2, no
// vmcnt(0) drain). part_acc aliases prep buffers (dead by flash time).

typedef __bf16 bf16_t;
typedef __bf16 bf16x8 __attribute__((ext_vector_type(8)));
typedef float f32x4 __attribute__((ext_vector_type(4)));
typedef float f32x16 __attribute__((ext_vector_type(16)));
typedef unsigned long long u64;

#define MFMA16(a, b, c) __builtin_amdgcn_mfma_f32_16x16x32_bf16((a), (b), (c), 0, 0, 0)
#define MFMA32(a, b, c) __builtin_amdgcn_mfma_f32_32x32x16_bf16((a), (b), (c), 0, 0, 0)
#define LOG2E 1.44269504088896340736f
#define SCALE_Q 0.18033688011112042f /* (1/8) * log2(e) */
#define SHIFT_C 8.0f                 /* fixed softmax shift (base-2 units) */
#define NSPLIT 8
#define KCHUNK 1152 /* 9216/8, 18 tiles of 64 */

typedef __attribute__((address_space(3))) unsigned int lds_uint;
typedef const __attribute__((address_space(1))) unsigned int glob_uint;
__device__ __forceinline__ void async_copy16(const void* g, void* l) {
  __builtin_amdgcn_global_load_lds((glob_uint*)g, (lds_uint*)l, 16, 0, 0);
}

// ---------------- fused prep: W transposes + bf16 casts ---------------------
// blocks 0..1727: transpose-cvt Wq/Wk/Wv -> wqkvT[n][k]
// blocks 1728+ : linear fp32->bf16 cvt of hid (576), memk (3456), memv (3456)
__global__ __launch_bounds__(256) void prep(
    const float* __restrict__ Wq, const float* __restrict__ Wk,
    const float* __restrict__ Wv, const float* __restrict__ hid,
    const float* __restrict__ memk, const float* __restrict__ memv,
    bf16_t* __restrict__ wqkvT, bf16_t* __restrict__ hidb,
    bf16_t* __restrict__ memkb, bf16_t* __restrict__ memvb) {
  const int id = blockIdx.x;
  const int tid = threadIdx.x;
  if (id < 1728) {
    __shared__ float t[32][33];
    const int z = id / 576, rem = id - z * 576;
    const int bx = (rem / 24) * 32, by = (rem % 24) * 32;
    const float* W = (z == 0) ? Wq : (z == 1) ? Wk : Wv;
    bf16_t* o = wqkvT + (size_t)z * 589824;
    const int tx = tid & 31, ty = tid >> 5;
#pragma unroll
    for (int i = 0; i < 32; i += 8) t[ty + i][tx] = W[(bx + ty + i) * 768 + by + tx];
    __syncthreads();
#pragma unroll
    for (int i = 0; i < 32; i += 8)
      o[(by + ty + i) * 768 + bx + tx] = (bf16_t)t[tx][ty + i];
  } else {
    int cid = id - 1728;
    const float* src;
    bf16_t* dst;
    if (cid < 576) {
      src = hid; dst = hidb;
    } else if (cid < 4032) {
      src = memk; dst = memkb; cid -= 576;
    } else {
      src = memv; dst = memvb; cid -= 4032;
    }
    const size_t off = (size_t)cid * 2048 + tid * 8;
    const float4 a = *(const float4*)(src + off);
    const float4 b = *(const float4*)(src + off + 4);
    bf16x8 o8;
    o8[0] = (bf16_t)a.x; o8[1] = (bf16_t)a.y; o8[2] = (bf16_t)a.z; o8[3] = (bf16_t)a.w;
    o8[4] = (bf16_t)b.x; o8[5] = (bf16_t)b.y; o8[6] = (bf16_t)b.z; o8[7] = (bf16_t)b.w;
    *(bf16x8*)(dst + off) = o8;
  }
}

// ---------------- canonical C[M][N] = A[M][K] * B[N][K]^T, bf16 MFMA --------
__device__ __forceinline__ bf16x8 cvt8u(const uint4 x, const uint4 y) {
  union { uint4 u; float f[4]; } a, b;
  a.u = x; b.u = y;
  bf16x8 o;
  o[0] = (bf16_t)a.f[0]; o[1] = (bf16_t)a.f[1];
  o[2] = (bf16_t)a.f[2]; o[3] = (bf16_t)a.f[3];
  o[4] = (bf16_t)b.f[0]; o[5] = (bf16_t)b.f[1];
  o[6] = (bf16_t)b.f[2]; o[7] = (bf16_t)b.f[3];
  return o;
}

// Double-buffered LDS, one barrier per 64-deep K slab, register prefetch.
template <int BM, int BN, bool AF32, bool BF32, typename EPI>
__device__ __forceinline__ void gemm_core(char* __restrict__ smem,
                                          const void* __restrict__ Ap, int lda,
                                          const void* __restrict__ Bp, int ldb,
                                          int K, int m0, int n0, EPI epi) {
  constexpr int MT = BM / 32;
  constexpr int NT = BN / 32;
  constexpr int AC = BM * 8 / 256;  // 16B chunks per thread (A)
  constexpr int BC = BN * 8 / 256;
  constexpr int HALF = (BM + BN) * 144;

  const int tid = threadIdx.x;
  const int lane = tid & 63;
  const int w = tid >> 6;
  const int l15 = lane & 15, quad = lane >> 4;
  const int wm = (w & 1) * (BM / 2);
  const int wn = (w >> 1) * (BN / 2);

  uint4 pa[AC][2], pb[BC][2];

  auto loadA = [&](int kk) {
#pragma unroll
    for (int i = 0; i < AC; ++i) {
      const int cidx = tid + i * 256, r = cidx >> 3, ch = cidx & 7;
      if constexpr (AF32) {
        const float* s = (const float*)Ap + (size_t)(m0 + r) * lda + kk + ch * 8;
        pa[i][0] = *(const uint4*)s;
        pa[i][1] = *(const uint4*)(s + 4);
      } else {
        const bf16_t* s = (const bf16_t*)Ap + (size_t)(m0 + r) * lda + kk + ch * 8;
        pa[i][0] = *(const uint4*)s;
      }
    }
  };
  auto loadB = [&](int kk) {
#pragma unroll
    for (int i = 0; i < BC; ++i) {
      const int cidx = tid + i * 256, r = cidx >> 3, ch = cidx & 7;
      if constexpr (BF32) {
        const float* s = (const float*)Bp + (size_t)(n0 + r) * ldb + kk + ch * 8;
        pb[i][0] = *(const uint4*)s;
        pb[i][1] = *(const uint4*)(s + 4);
      } else {
        const bf16_t* s = (const bf16_t*)Bp + (size_t)(n0 + r) * ldb + kk + ch * 8;
        pb[i][0] = *(const uint4*)s;
      }
    }
  };
  auto store = [&](char* base) {
    char* sA = base;
    char* sB = base + BM * 144;
#pragma unroll
    for (int i = 0; i < AC; ++i) {
      const int cidx = tid + i * 256, r = cidx >> 3, ch = cidx & 7;
      if constexpr (AF32)
        *(bf16x8*)(sA + r * 144 + ch * 16) = cvt8u(pa[i][0], pa[i][1]);
      else
        *(uint4*)(sA + r * 144 + ch * 16) = pa[i][0];
    }
#pragma unroll
    for (int i = 0; i < BC; ++i) {
      const int cidx = tid + i * 256, r = cidx >> 3, ch = cidx & 7;
      if constexpr (BF32)
        *(bf16x8*)(sB + r * 144 + ch * 16) = cvt8u(pb[i][0], pb[i][1]);
      else
        *(uint4*)(sB + r * 144 + ch * 16) = pb[i][0];
    }
  };

  const f32x4 fzero = {0.f, 0.f, 0.f, 0.f};
  f32x4 acc[MT][NT];
#pragma unroll
  for (int i = 0; i < MT; ++i)
#pragma unroll
    for (int j = 0; j < NT; ++j) acc[i][j] = fzero;

  const int NS = K / 64;
  loadA(0);
  loadB(0);
  store(smem);

  for (int t = 0; t < NS; ++t) {
    char* base = smem + (t & 1) * HALF;
    char* sA = base;
    char* sB = base + BM * 144;
    __syncthreads();
    if (t + 1 < NS) {
      loadA((t + 1) * 64);
      loadB((t + 1) * 64);
    }
#pragma unroll
    for (int ks = 0; ks < 2; ++ks) {
      bf16x8 af[MT], bfr[NT];
#pragma unroll
      for (int i = 0; i < MT; ++i)
        af[i] = *(const bf16x8*)(sA + (wm + i * 16 + l15) * 144 + ks * 64 + quad * 16);
#pragma unroll
      for (int j = 0; j < NT; ++j)
        bfr[j] = *(const bf16x8*)(sB + (wn + j * 16 + l15) * 144 + ks * 64 + quad * 16);
#pragma unroll
      for (int i = 0; i < MT; ++i)
#pragma unroll
        for (int j = 0; j < NT; ++j) acc[i][j] = MFMA16(af[i], bfr[j], acc[i][j]);
    }
    if (t + 1 < NS) store(smem + ((t + 1) & 1) * HALF);
  }
#pragma unroll
  for (int i = 0; i < MT; ++i)
#pragma unroll
    for (int j = 0; j < NT; ++j)
#pragma unroll
      for (int p = 0; p < 4; ++p)
        epi(m0 + wm + i * 16 + quad * 4 + p, n0 + wn + j * 16 + l15, acc[i][j][p]);
}

// Merged QKV projections (64x64 tiles, dbuf, all-bf16 operands).
__global__ __launch_bounds__(256) void gemm_qkv(const bf16_t* __restrict__ hidb,
                                                const bf16_t* __restrict__ wT,
                                                const float* __restrict__ bq,
                                                const float* __restrict__ bk,
                                                const float* __restrict__ bv,
                                                bf16_t* __restrict__ q,
                                                bf16_t* __restrict__ ktvt) {
  __shared__ __align__(16) char smem[2 * (64 + 64) * 144];
  if (blockIdx.y < 12) {
    const int m0 = blockIdx.x * 64, n0 = blockIdx.y * 64;
    auto epi = [=](int m, int n, float v) {
      const int b = m / 768, s = m - b * 768;
      const int h = n >> 6, d = n & 63;
      q[((size_t)((b * 12 + h) * 768 + s) << 6) + d] = (bf16_t)((v + bq[n]) * SCALE_Q);
    };
    gemm_core<64, 64, false, false>(smem, hidb, 768, wT, 768, 768, m0, n0, epi);
  } else {
    const int m0 = blockIdx.x * 64, n0 = (blockIdx.y - 12) * 64;
    auto epi = [=](int m, int n, float v) {
      const float bias = (m < 768) ? bk[m] : bv[m - 768];
      ktvt[(size_t)m * 1536 + n] = (bf16_t)(v + bias);
    };
    gemm_core<64, 64, false, false>(smem, wT + 589824, 768, hidb, 768, 768, m0, n0, epi);
  }
}

// Merged memory GEMMs (64x64 tiles, dbuf, all-bf16 operands).
__global__ __launch_bounds__(256) void gemm_mem(const bf16_t* __restrict__ memkb,
                                                const bf16_t* __restrict__ memvb,
                                                const bf16_t* __restrict__ ktvt,
                                                bf16_t* __restrict__ kc,
                                                bf16_t* __restrict__ vct) {
  __shared__ __align__(16) char smem[2 * (64 + 64) * 144];
  const int z = blockIdx.z, b = z / 12, h = z - (z / 12) * 12;
  if (blockIdx.y == 0) {
    const int m0 = blockIdx.x * 64;
    const bf16_t* A = memkb + (size_t)h * 589824;
    const bf16_t* B = ktvt + (size_t)(h * 64) * 1536 + b * 768;
    bf16_t* outp = kc + (size_t)b * 589824 + (size_t)h * 768 * 64;
    auto epi = [=](int m, int n, float v) { outp[((size_t)m << 6) + n] = (bf16_t)v; };
    gemm_core<64, 64, false, false>(smem, A, 768, B, 1536, 768, m0, 0, epi);
  } else {
    const int n0 = blockIdx.x * 64;
    const bf16_t* A = ktvt + (size_t)(768 + h * 64) * 1536 + b * 768;
    const bf16_t* B = memvb + (size_t)h * 589824;
    bf16_t* outp = vct + (size_t)b * 589824 + h * 768;
    auto epi = [=](int m, int n, float v) { outp[(size_t)m * 9216 + n] = (bf16_t)v; };
    gemm_core<64, 64, false, false>(smem, A, 1536, B, 768, 768, 0, n0, epi);
  }
}

// ---------------- flash attention, split-K, 32x32 MFMA, transposed-S -------
// 128-thread blocks (2 waves x 64 q-rows). Grid (6,12,16), z=(b,c) slowest.
// Triple-buffered DMA staging, prefetch distance 2. Per tile: each wave waits
// only ITS oldest 8 DMAs (vmcnt(8) -> tile t landed; tile t+1/t+2 stay in
// flight), then raw s_barrier. Wave 0 stages Kc, wave 1 V^T. XOR swizzle:
// LDS (row,pc) holds global chunk pc^(row&7); readers apply the same XOR.
__global__ __launch_bounds__(128, 2) void flash_attn_split(
    const bf16_t* __restrict__ q, const bf16_t* __restrict__ kc,
    const bf16_t* __restrict__ vct, const float* __restrict__ mask,
    float* __restrict__ part_acc, float* __restrict__ part_l) {
  const int qt = blockIdx.x, h = blockIdx.y;
  const int z = blockIdx.z, b = z >> 3, c = z & 7;
  const int tid = threadIdx.x;
  const int w = tid >> 6, lane = tid & 63, l31 = lane & 31, h5 = lane >> 5;

  __shared__ __align__(16) bf16_t kc_s[3][64 * 64];  // 3 bufs, 128B rows
  __shared__ __align__(16) bf16_t vt_s[3][64 * 64];
  __shared__ float w_all[KCHUNK];

  const bf16_t* kcb = kc + (size_t)b * 589824;
  const bf16_t* vtb = vct + (size_t)b * 589824;
  const float* mkb = mask + b * 9216;
  const int k00 = c * KCHUNK;

  // Q B-frags, held for the whole kernel
  const int q0 = qt * 128 + w * 64;
  bf16x8 qf[2][4];
#pragma unroll
  for (int nb = 0; nb < 2; ++nb) {
    const bf16_t* qp =
        q + ((size_t)((b * 12 + h) * 768 + q0 + nb * 32 + l31) << 6) + h5 * 8;
#pragma unroll
    for (int kd = 0; kd < 4; ++kd) qf[nb][kd] = *(const bf16x8*)(qp + kd * 16);
  }

  // async staging: wave 0 -> kc tile, wave 1 -> vt tile (8 DMA issues each)
  auto stage = [&](int t, int buf) {
    const int k0 = k00 + t * 64;
#pragma unroll
    for (int i = 0; i < 8; ++i) {
      const int p = i * 64 + lane;   // LDS 16B-chunk position
      const int r = p >> 3;          // row 0..63
      const int gc = (p & 7) ^ (r & 7);
      if (w == 0)
        async_copy16(kcb + ((size_t)(k0 + r) << 6) + gc * 8,
                     (char*)&kc_s[buf][0] + p * 16);
      else
        async_copy16(vtb + (size_t)r * 9216 + k0 + gc * 8,
                     (char*)&vt_s[buf][0] + p * 16);
    }
  };

  stage(0, 0);
  stage(1, 1);
  for (int i = tid; i < KCHUNK; i += 128)
    w_all[i] = exp2f(fmaf(mkb[k00 + i], LOG2E, -SHIFT_C));

  f32x16 o[2][2];
#pragma unroll
  for (int nb = 0; nb < 2; ++nb)
#pragma unroll
    for (int md = 0; md < 2; ++md)
#pragma unroll
      for (int r = 0; r < 16; ++r) o[nb][md][r] = 0.f;
  float rsum[2] = {0.f, 0.f};

  __syncthreads();  // one-time full drain: tiles 0,1 + w_all ready

  for (int t = 0; t < KCHUNK / 64; ++t) {
    if (t > 0) {
      asm volatile("" ::: "memory");
      if (t + 1 < KCHUNK / 64)
        __builtin_amdgcn_s_waitcnt(0x0F78);  // vmcnt(8): tile t landed
      else
        __builtin_amdgcn_s_waitcnt(0x0F70);  // last tile: vmcnt(0)
      __builtin_amdgcn_s_barrier();
      asm volatile("" ::: "memory");
    }
    if (t + 2 < KCHUNK / 64) stage(t + 2, (t + 2) % 3);

    const int cur = t % 3;
    const char* kcS = (const char*)&kc_s[cur][0];
    const char* vtS = (const char*)&vt_s[cur][0];
    const float* wt = w_all + t * 64;

#pragma unroll
    for (int mb = 0; mb < 2; ++mb) {  // 32-key block
      bf16x8 ka[4];
#pragma unroll
      for (int kd = 0; kd < 4; ++kd) {
        const int r = mb * 32 + l31;
        const int cc = (kd * 2 + h5) ^ (r & 7);
        ka[kd] = *(const bf16x8*)(kcS + r * 128 + cc * 16);
      }
      bf16x8 va[2][2];
#pragma unroll
      for (int md = 0; md < 2; ++md)
#pragma unroll
        for (int tt = 0; tt < 2; ++tt) {
          const int r = md * 32 + l31;
          const int c0 = mb * 4 + tt * 2;
          const char* vb = vtS + r * 128 + h5 * 8;
          union { u64 u[2]; bf16x8 v; } tmp;
          tmp.u[0] = *(const u64*)(vb + ((c0 ^ (r & 7)) << 4));
          tmp.u[1] = *(const u64*)(vb + (((c0 + 1) ^ (r & 7)) << 4));
          va[md][tt] = tmp.v;
        }
      float wv[16];
#pragma unroll
      for (int g = 0; g < 4; ++g) {
        const float4 t4 = *(const float4*)(wt + mb * 32 + h5 * 4 + g * 8);
        wv[g * 4 + 0] = t4.x; wv[g * 4 + 1] = t4.y;
        wv[g * 4 + 2] = t4.z; wv[g * 4 + 3] = t4.w;
      }
#pragma unroll
      for (int nb = 0; nb < 2; ++nb) {
        f32x16 s;
#pragma unroll
        for (int r = 0; r < 16; ++r) s[r] = 0.f;
#pragma unroll
        for (int kd = 0; kd < 4; ++kd) s = MFMA32(ka[kd], qf[nb][kd], s);
        float pw[16];
#pragma unroll
        for (int r = 0; r < 16; ++r) {
          const float pv2 = __builtin_amdgcn_exp2f(s[r]) * wv[r];
          rsum[nb] += pv2;
          pw[r] = pv2;
        }
        bf16x8 pb0, pb1;
#pragma unroll
        for (int j = 0; j < 8; ++j) {
          pb0[j] = (bf16_t)pw[j];
          pb1[j] = (bf16_t)pw[8 + j];
        }
#pragma unroll
        for (int md = 0; md < 2; ++md) {
          o[nb][md] = MFMA32(va[md][0], pb0, o[nb][md]);
          o[nb][md] = MFMA32(va[md][1], pb1, o[nb][md]);
        }
      }
    }
  }

  const float l0 = rsum[0] + __shfl_xor(rsum[0], 32);
  const float l1 = rsum[1] + __shfl_xor(rsum[1], 32);

  const int pidx = ((b * 12 + h) * 6 + qt) * NSPLIT + c;
  float* pacc = part_acc + (size_t)pidx * 8192;
#pragma unroll
  for (int nb = 0; nb < 2; ++nb) {
    const int ql = w * 64 + nb * 32 + l31;
#pragma unroll
    for (int md = 0; md < 2; ++md)
#pragma unroll
      for (int g = 0; g < 4; ++g) {
        float4 v;
        v.x = o[nb][md][g * 4 + 0];
        v.y = o[nb][md][g * 4 + 1];
        v.z = o[nb][md][g * 4 + 2];
        v.w = o[nb][md][g * 4 + 3];
        *(float4*)(pacc + (size_t)ql * 64 + md * 32 + h5 * 4 + g * 8) = v;
      }
  }
  if (h5 == 0) {
    part_l[(size_t)pidx * 128 + w * 64 + l31] = l0;
    part_l[(size_t)pidx * 128 + w * 64 + 32 + l31] = l1;
  }
}

// ---------------- combine split-K partials, normalize, gate, write out -----
__global__ __launch_bounds__(256) void flash_combine(
    const float* __restrict__ part_acc, const float* __restrict__ part_l,
    const float* __restrict__ gate, float* __restrict__ out) {
  const int x = blockIdx.x, h = blockIdx.y, b = blockIdx.z;  // grid (24,12,2)
  const int qt = x >> 2, rq = x & 3;
  const int tid = threadIdx.x;
  const int row = rq * 32 + (tid >> 3), dseg = tid & 7;  // row 0..127
  const int base = ((b * 12 + h) * 6 + qt) * NSPLIT;

  float L = 0.f;
#pragma unroll
  for (int ci = 0; ci < NSPLIT; ++ci) L += part_l[(size_t)(base + ci) * 128 + row];

  f32x4 a0 = {0.f, 0.f, 0.f, 0.f}, a1 = {0.f, 0.f, 0.f, 0.f};
#pragma unroll
  for (int ci = 0; ci < NSPLIT; ++ci) {
    const float* p = part_acc + (size_t)(base + ci) * 8192 + row * 64 + dseg * 8;
    const float4 v0 = *(const float4*)p;
    const float4 v1 = *(const float4*)(p + 4);
    a0[0] += v0.x; a0[1] += v0.y; a0[2] += v0.z; a0[3] += v0.w;
    a1[0] += v1.x; a1[1] += v1.y; a1[2] += v1.z; a1[3] += v1.w;
  }
  const float g = 1.f / (1.f + expf(-gate[h]));
  const float sc = g / L;
  float* op =
      out + ((size_t)((b * 768 + qt * 128 + row) * 12 + h) << 6) + dseg * 8;
  float4 w0, w1;
  w0.x = a0[0] * sc; w0.y = a0[1] * sc; w0.z = a0[2] * sc; w0.w = a0[3] * sc;
  w1.x = a1[0] * sc; w1.y = a1[1] * sc; w1.z = a1[2] * sc; w1.w = a1[3] * sc;
  *(float4*)op = w0;
  *(float4*)(op + 4) = w1;
}

extern "C" void kernel_launch(void* const* d_in, const int* in_sizes, int n_in,
                              void* d_out, int out_size, void* d_ws, size_t ws_size,
                              hipStream_t stream) {
  const float* hid  = (const float*)d_in[0];
  const float* mask = (const float*)d_in[1];
  const float* Wq   = (const float*)d_in[2];
  const float* bq   = (const float*)d_in[3];
  const float* Wk   = (const float*)d_in[4];
  const float* bk   = (const float*)d_in[5];
  const float* Wv   = (const float*)d_in[6];
  const float* bv   = (const float*)d_in[7];
  const float* gate = (const float*)d_in[8];
  const float* memk = (const float*)d_in[9];
  const float* memv = (const float*)d_in[10];
  float* out = (float*)d_out;

  // workspace layout (peak 53.67 MB, unchanged):
  //   part_acc ALIASES hidb/memkb/memvb (those are dead once gemm_mem ends).
  char* ws = (char*)d_ws;
  bf16_t* wqkvT    = (bf16_t*)(ws);             // [2304][768] bf16
  bf16_t* qb       = (bf16_t*)(ws + 3538944);   // q [2][12][768][64] bf16
  bf16_t* ktvt     = (bf16_t*)(ws + 5898240);   // [1536][1536] bf16
  bf16_t* kcw      = (bf16_t*)(ws + 10616832);  // kc [2][9216][64] bf16
  bf16_t* vct      = (bf16_t*)(ws + 12976128);  // vc^T [2][64][9216] bf16
  bf16_t* hidb     = (bf16_t*)(ws + 15335424);  // [1536][768] bf16
  bf16_t* memkb    = (bf16_t*)(ws + 17694720);  // [12][768][768] bf16
  bf16_t* memvb    = (bf16_t*)(ws + 31850496);  // [12][768][768] bf16
  float*  part_acc = (float*)(ws + 15335424);   // [1152][128][64] fp32 (alias)
  float*  part_l   = (float*)(ws + 53084160);   // [1152][128] fp32

  prep<<<dim3(9216), 256, 0, stream>>>(Wq, Wk, Wv, hid, memk, memv,
                                       wqkvT, hidb, memkb, memvb);
  gemm_qkv<<<dim3(24, 36), 256, 0, stream>>>(hidb, wqkvT, bq, bk, bv, qb, ktvt);
  gemm_mem<<<dim3(12, 2, 24), 256, 0, stream>>>(memkb, memvb, ktvt, kcw, vct);
  flash_attn_split<<<dim3(6, 12, 16), 128, 0, stream>>>(qb, kcw, vct, mask,
                                                        part_acc, part_l);
  flash_combine<<<dim3(24, 12, 2), 256, 0, stream>>>(part_acc, part_l, gate, out);
}